// Round 11
// baseline (119.365 us; speedup 1.0000x reference)
//
#include <hip/hip_runtime.h>
#include <math.h>

#define LRES 2048
#define NB 8
#define KSEL 64
#define EMBD 16
#define NBIN 100     // bin = trunc(d2); 100 = sentinel (excluded / out of cutoff)
#define NSLOT 10     // per-lane capture slots; Poisson(2) tail negligible

#define LDS_FENCE() asm volatile("s_waitcnt lgkmcnt(0)" ::: "memory")

// prep: rho + pack (x,y,z,rho) as float4; zero output accumulators
__global__ void prep_kernel(const float* __restrict__ R,
                            const int* __restrict__ seq,
                            const float* __restrict__ emb,
                            const float* __restrict__ w,
                            const float* __restrict__ bias,
                            float4* __restrict__ pts,
                            float* __restrict__ out) {
    int idx = blockIdx.x * blockDim.x + threadIdx.x;
    if (idx < NB) out[idx] = 0.0f;
    if (idx < NB * LRES) {
        int s = seq[idx];
        float x = bias[0];
#pragma unroll
        for (int d = 0; d < EMBD; ++d) x += emb[s * EMBD + d] * w[d];
        float rho = 1.6f + 1.2f / (1.0f + expf(-x));
        pts[idx] = make_float4(R[3 * idx], R[3 * idx + 1], R[3 * idx + 2], rho);
    }
}

// 256 threads = 4 waves; 2 rows per wave; bins held as packed u8 in 16 VGPRs
__global__ __launch_bounds__(256, 4) void repel_kernel(const float4* __restrict__ pts,
                                                       float* __restrict__ out) {
    const int tid  = threadIdx.x;
    const int w    = tid >> 6;
    const int lane = tid & 63;
    const int blk  = blockIdx.x;
    const int b    = blk >> 8;                        // 256 blocks per batch
    const int iw   = ((blk & 255) << 3) + (w << 1);   // this wave's first row

    __shared__ unsigned hist[4][NBIN];                // packed: lo16 = row0, hi16 = row1
    __shared__ unsigned short slots[4][NSLOT][64];    // [slot][lane] -> conflict-free
    __shared__ unsigned shT[4][2];
    __shared__ float shred[4];

    const float4* __restrict__ P = pts + (b << 11);

    if (lane < 50) { hist[w][2 * lane] = 0u; hist[w][2 * lane + 1] = 0u; }
    if (lane < 2) shT[w][lane] = NBIN - 1;            // default: select all in-cutoff

    const float4 c0 = P[iw];
    const float4 c1 = P[iw + 1];

    // ---- pass A: distances -> byte-packed bins (pure VALU; 16 u32 of state) ----
    unsigned pk0[8], pk1[8];
#pragma unroll
    for (int g = 0; g < 8; ++g) {
        unsigned a0 = 0u, a1 = 0u;
#pragma unroll
        for (int e = 0; e < 4; ++e) {
            int j = ((4 * g + e) << 6) + lane;
            float4 p = P[j];
            float dx0 = p.x - c0.x, dy0 = p.y - c0.y, dz0 = p.z - c0.z;
            float q0 = dx0 * dx0 + dy0 * dy0 + dz0 * dz0;
            float dx1 = p.x - c1.x, dy1 = p.y - c1.y, dz1 = p.z - c1.z;
            float q1 = dx1 * dx1 + dy1 * dy1 + dz1 * dz1;
            int u0 = j - iw;     u0 = (u0 < 0) ? -u0 : u0;
            int u1 = j - iw - 1; u1 = (u1 < 0) ? -u1 : u1;
            unsigned b0 = (unsigned)fminf(q0, 100.0f);   // 0..99 real, 100 = out
            unsigned b1 = (unsigned)fminf(q1, 100.0f);
            if (u0 <= 2) b0 = 100u;
            if (u1 <= 2) b1 = 100u;
            a0 |= b0 << (8 * e);
            a1 |= b1 << (8 * e);
        }
        pk0[g] = a0; pk1[g] = a1;
    }
    LDS_FENCE();                                      // hist zero-init done

    // ---- pass B: histogram (predicated fire-and-forget ds_add) ----
#pragma unroll
    for (int g = 0; g < 8; ++g) {
        unsigned a0 = pk0[g], a1 = pk1[g];
#pragma unroll
        for (int e = 0; e < 4; ++e) {
            unsigned b0 = (a0 >> (8 * e)) & 0xFFu;
            unsigned b1 = (a1 >> (8 * e)) & 0xFFu;
            if (b0 < 100u) atomicAdd(&hist[w][b0], 1u);        // row0 -> lo16
            if (b1 < 100u) atomicAdd(&hist[w][b1], 0x10000u);  // row1 -> hi16
        }
    }
    LDS_FENCE();                                      // own-wave atomics complete

    // ---- one packed scan serves both rows (counts < 2048 per half: no carry) ----
    uint2 hv = (lane < 50) ? *(const uint2*)&hist[w][lane << 1] : make_uint2(0u, 0u);
    unsigned pp = hv.x + hv.y;
    unsigned s = pp;
#pragma unroll
    for (int o = 1; o < 64; o <<= 1) {
        unsigned u = __shfl_up(s, o, 64);
        if (lane >= o) s += u;
    }
    unsigned e = s - pp;
    {   // row0: lo16
        unsigned s0 = s & 0xFFFFu, e0 = e & 0xFFFFu, h0 = hv.x & 0xFFFFu;
        if (s0 >= KSEL && e0 < KSEL)
            shT[w][0] = (e0 + h0 >= KSEL) ? (unsigned)(lane << 1) : (unsigned)(lane << 1) + 1u;
    }
    {   // row1: hi16
        unsigned s1 = s >> 16, e1 = e >> 16, h1 = hv.x >> 16;
        if (s1 >= KSEL && e1 < KSEL)
            shT[w][1] = (e1 + h1 >= KSEL) ? (unsigned)(lane << 1) : (unsigned)(lane << 1) + 1u;
    }
    LDS_FENCE();
    const unsigned T0 = shT[w][0];                    // whole boundary bin selected
    const unsigned T1 = shT[w][1];

    // ---- capture: bin <= T -> private conflict-free u16 slots ----
    unsigned cnt = 0;
#pragma unroll
    for (int g = 0; g < 8; ++g) {
        unsigned a0 = pk0[g], a1 = pk1[g];
#pragma unroll
        for (int e = 0; e < 4; ++e) {
            int j = ((4 * g + e) << 6) + lane;
            unsigned b0 = (a0 >> (8 * e)) & 0xFFu;
            unsigned b1 = (a1 >> (8 * e)) & 0xFFu;
            if (b0 <= T0 && cnt < NSLOT) { slots[w][cnt][lane] = (unsigned short)j; ++cnt; }
            if (b1 <= T1 && cnt < NSLOT) { slots[w][cnt][lane] = (unsigned short)(0x800 | j); ++cnt; }
        }
    }
    LDS_FENCE();

    // ---- eval own slots (~2/lane): recompute d2 fp32, full energy ----
    float acc = 0.0f;
    for (unsigned k = 0; k < cnt; ++k) {
        unsigned u = slots[w][k][lane];
        unsigned j = u & 2047u;
        bool r1 = (u & 0x800u) != 0u;
        float4 pj = P[j];
        float cx = r1 ? c1.x : c0.x, cy = r1 ? c1.y : c0.y;
        float cz = r1 ? c1.z : c0.z, ri = r1 ? c1.w : c0.w;
        float dx = pj.x - cx, dy = pj.y - cy, dz = pj.z - cz;
        float d2 = dx * dx + dy * dy + dz * dz;
        float rr = __fsqrt_rn(fmaxf(d2, 1e-12f));
        float x = (ri + pj.w - rr) * (1.0f / 0.3f);
        float sp = fmaxf(x, 0.0f) + __logf(1.0f + __expf(-fabsf(x)));
        float t = fminf(fmaxf((rr - 8.0f) * 0.5f, 0.0f), 1.0f);
        float sw = 1.0f - t * t * (3.0f - 2.0f * t);
        acc += 10.0f * sp * sw;
    }

    // ---- block reduce + one global atomic per block ----
#pragma unroll
    for (int o = 32; o > 0; o >>= 1) acc += __shfl_down(acc, o, 64);
    if (lane == 0) shred[w] = acc;
    __syncthreads();
    if (tid == 0) atomicAdd(out + b, shred[0] + shred[1] + shred[2] + shred[3]);
}

extern "C" void kernel_launch(void* const* d_in, const int* in_sizes, int n_in,
                              void* d_out, int out_size, void* d_ws, size_t ws_size,
                              hipStream_t stream) {
    const float* R    = (const float*)d_in[0];   // (8, 2048, 3) f32
    const int*   seq  = (const int*)d_in[1];     // (8, 2048) int
    const float* emb  = (const float*)d_in[2];   // (20, 16) f32
    const float* w    = (const float*)d_in[3];   // (1, 16) f32
    const float* bias = (const float*)d_in[4];   // (1,) f32
    float* out = (float*)d_out;                  // (8,) f32
    float4* pts = (float4*)d_ws;                 // 16384 float4 = 256 KB

    prep_kernel<<<(NB * LRES + 255) / 256, 256, 0, stream>>>(R, seq, emb, w, bias, pts, out);
    repel_kernel<<<NB * 256, 256, 0, stream>>>(pts, out);
}

// Round 12
// 106.820 us; speedup vs baseline: 1.1174x; 1.1174x over previous
//
#include <hip/hip_runtime.h>
#include <math.h>

#define LRES 2048
#define NB 8
#define KSEL 64
#define EMBD 16
#define NBIN 100     // bin = trunc(d2); 100+ = sentinel (excluded / out of cutoff)
#define NSLOT 14     // per-lane capture slots; Poisson(~3) tail ~1e-6 per lane

#define LDS_FENCE() asm volatile("s_waitcnt lgkmcnt(0)" ::: "memory")

// prep: rho + pack (x,y,z,rho) as float4; zero output accumulators
__global__ void prep_kernel(const float* __restrict__ R,
                            const int* __restrict__ seq,
                            const float* __restrict__ emb,
                            const float* __restrict__ w,
                            const float* __restrict__ bias,
                            float4* __restrict__ pts,
                            float* __restrict__ out) {
    int idx = blockIdx.x * blockDim.x + threadIdx.x;
    if (idx < NB) out[idx] = 0.0f;
    if (idx < NB * LRES) {
        int s = seq[idx];
        float x = bias[0];
#pragma unroll
        for (int d = 0; d < EMBD; ++d) x += emb[s * EMBD + d] * w[d];
        float rho = 1.6f + 1.2f / (1.0f + expf(-x));
        pts[idx] = make_float4(R[3 * idx], R[3 * idx + 1], R[3 * idx + 2], rho);
    }
}

// 256 threads = 4 waves; 2 rows per wave; bins live in LDS (no big register arrays)
__global__ __launch_bounds__(256) void repel_kernel(const float4* __restrict__ pts,
                                                    float* __restrict__ out) {
    const int tid  = threadIdx.x;
    const int w    = tid >> 6;
    const int lane = tid & 63;
    const int blk  = blockIdx.x;
    const int b    = blk >> 8;                        // 256 blocks per batch
    const int iw   = ((blk & 255) << 3) + (w << 1);   // this wave's first row

    __shared__ unsigned hist[4][NBIN];                // packed: lo16 = row0, hi16 = row1
    __shared__ unsigned bins[4][2][512];              // 16 KB; 4 u8 bins per u32
    __shared__ unsigned short slots[4][NSLOT][64];    // 7 KB; [slot][lane] conflict-free
    __shared__ unsigned shT[4][2];
    __shared__ float shred[4];

    const float4* __restrict__ P = pts + (b << 11);

    if (lane < 50) { hist[w][2 * lane] = 0u; hist[w][2 * lane + 1] = 0u; }
    if (lane < 2) shT[w][lane] = NBIN - 1;            // default: select all in-cutoff

    const float4 c0 = P[iw];
    const float4 c1 = P[iw + 1];
    LDS_FENCE();                                      // hist zero-init done (own wave)

    // ---- pass A: lane owns 4 consecutive j's per g; bins -> LDS; hist atomics ----
    // unroll 1: keeps at most 4 float4 loads live -> no register-array spill
#pragma unroll 1
    for (int g = 0; g < 8; ++g) {
        int j0 = (g << 8) + (lane << 2);
        float4 p0 = P[j0 + 0];
        float4 p1 = P[j0 + 1];
        float4 p2 = P[j0 + 2];
        float4 p3 = P[j0 + 3];
        unsigned a0 = 0u, a1 = 0u;
#pragma unroll
        for (int e = 0; e < 4; ++e) {
            float4 p = (e == 0) ? p0 : (e == 1) ? p1 : (e == 2) ? p2 : p3;
            int j = j0 + e;
            float dx0 = p.x - c0.x, dy0 = p.y - c0.y, dz0 = p.z - c0.z;
            float q0 = dx0 * dx0 + dy0 * dy0 + dz0 * dz0;
            float dx1 = p.x - c1.x, dy1 = p.y - c1.y, dz1 = p.z - c1.z;
            float q1 = dx1 * dx1 + dy1 * dy1 + dz1 * dz1;
            int u0 = j - iw;     u0 = (u0 < 0) ? -u0 : u0;
            int u1 = j - iw - 1; u1 = (u1 < 0) ? -u1 : u1;
            unsigned b0 = (unsigned)fminf(q0, 100.0f);   // 0..99 real, 100 = out
            unsigned b1 = (unsigned)fminf(q1, 100.0f);
            if (u0 <= 2) b0 = 100u;
            if (u1 <= 2) b1 = 100u;
            a0 |= b0 << (8 * e);
            a1 |= b1 << (8 * e);
            if (b0 < 100u) atomicAdd(&hist[w][b0], 1u);        // row0 -> lo16
            if (b1 < 100u) atomicAdd(&hist[w][b1], 0x10000u);  // row1 -> hi16
        }
        bins[w][0][(g << 6) + lane] = a0;             // consecutive dwords: conflict-free
        bins[w][1][(g << 6) + lane] = a1;
    }
    LDS_FENCE();                                      // own-wave atomics+writes complete

    // ---- one packed scan serves both rows (counts < 2048 per half: no carry) ----
    uint2 hv = (lane < 50) ? *(const uint2*)&hist[w][lane << 1] : make_uint2(0u, 0u);
    unsigned pp = hv.x + hv.y;
    unsigned s = pp;
#pragma unroll
    for (int o = 1; o < 64; o <<= 1) {
        unsigned u = __shfl_up(s, o, 64);
        if (lane >= o) s += u;
    }
    unsigned e = s - pp;
    {   // row0: lo16
        unsigned s0 = s & 0xFFFFu, e0 = e & 0xFFFFu, h0 = hv.x & 0xFFFFu;
        if (s0 >= KSEL && e0 < KSEL)
            shT[w][0] = (e0 + h0 >= KSEL) ? (unsigned)(lane << 1) : (unsigned)(lane << 1) + 1u;
    }
    {   // row1: hi16
        unsigned s1 = s >> 16, e1 = e >> 16, h1 = hv.x >> 16;
        if (s1 >= KSEL && e1 < KSEL)
            shT[w][1] = (e1 + h1 >= KSEL) ? (unsigned)(lane << 1) : (unsigned)(lane << 1) + 1u;
    }
    LDS_FENCE();
    const unsigned T0 = shT[w][0];                    // whole boundary bin selected
    const unsigned T1 = shT[w][1];

    // ---- capture: read bins back; bin <= T -> private conflict-free u16 slots ----
    unsigned cnt = 0;
#pragma unroll 1
    for (int g = 0; g < 8; ++g) {
        unsigned a0 = bins[w][0][(g << 6) + lane];
        unsigned a1 = bins[w][1][(g << 6) + lane];
        int j0 = (g << 8) + (lane << 2);
#pragma unroll
        for (int e2 = 0; e2 < 4; ++e2) {
            unsigned b0 = (a0 >> (8 * e2)) & 0xFFu;
            unsigned b1 = (a1 >> (8 * e2)) & 0xFFu;
            if (b0 <= T0 && cnt < NSLOT) { slots[w][cnt][lane] = (unsigned short)(j0 + e2); ++cnt; }
            if (b1 <= T1 && cnt < NSLOT) { slots[w][cnt][lane] = (unsigned short)(0x800 | (j0 + e2)); ++cnt; }
        }
    }
    LDS_FENCE();

    // ---- eval own slots (~3/lane): recompute d2 fp32 from L1-hot P[j] ----
    float acc = 0.0f;
    for (unsigned k = 0; k < cnt; ++k) {
        unsigned u = slots[w][k][lane];
        unsigned j = u & 2047u;
        bool r1 = (u & 0x800u) != 0u;
        float4 pj = P[j];
        float cx = r1 ? c1.x : c0.x, cy = r1 ? c1.y : c0.y;
        float cz = r1 ? c1.z : c0.z, ri = r1 ? c1.w : c0.w;
        float dx = pj.x - cx, dy = pj.y - cy, dz = pj.z - cz;
        float d2 = dx * dx + dy * dy + dz * dz;
        float rr = __fsqrt_rn(fmaxf(d2, 1e-12f));
        float x = (ri + pj.w - rr) * (1.0f / 0.3f);
        float sp = fmaxf(x, 0.0f) + __logf(1.0f + __expf(-fabsf(x)));
        float t = fminf(fmaxf((rr - 8.0f) * 0.5f, 0.0f), 1.0f);
        float sw = 1.0f - t * t * (3.0f - 2.0f * t);
        acc += 10.0f * sp * sw;
    }

    // ---- block reduce + one global atomic per block ----
#pragma unroll
    for (int o = 32; o > 0; o >>= 1) acc += __shfl_down(acc, o, 64);
    if (lane == 0) shred[w] = acc;
    __syncthreads();
    if (tid == 0) atomicAdd(out + b, shred[0] + shred[1] + shred[2] + shred[3]);
}

extern "C" void kernel_launch(void* const* d_in, const int* in_sizes, int n_in,
                              void* d_out, int out_size, void* d_ws, size_t ws_size,
                              hipStream_t stream) {
    const float* R    = (const float*)d_in[0];   // (8, 2048, 3) f32
    const int*   seq  = (const int*)d_in[1];     // (8, 2048) int
    const float* emb  = (const float*)d_in[2];   // (20, 16) f32
    const float* w    = (const float*)d_in[3];   // (1, 16) f32
    const float* bias = (const float*)d_in[4];   // (1,) f32
    float* out = (float*)d_out;                  // (8,) f32
    float4* pts = (float4*)d_ws;                 // 16384 float4 = 256 KB

    prep_kernel<<<(NB * LRES + 255) / 256, 256, 0, stream>>>(R, seq, emb, w, bias, pts, out);
    repel_kernel<<<NB * 256, 256, 0, stream>>>(pts, out);
}